// Round 13
// baseline (3027.234 us; speedup 1.0000x reference)
//
#include <hip/hip_runtime.h>
#include <hip/hip_bf16.h>

// Problem constants
#define BATCH   64
#define SEQ     512
#define IN0     512
#define HID     128
#define G3      384   // 3*HID
#define NLAY    5
#define CHUNK   8     // handoff granularity (one release/acquire per CHUNK steps)

typedef _Float16 f16x8 __attribute__((ext_vector_type(8)));
typedef float    f32x4 __attribute__((ext_vector_type(4)));

static __device__ __forceinline__ float sigf(float x) {
    return __builtin_amdgcn_rcpf(1.f + __expf(-x));
}
static __device__ __forceinline__ float tanh_fast(float x) {
    const float e = __expf(-2.f * fabsf(x));
    return copysignf((1.f - e) * __builtin_amdgcn_rcpf(1.f + e), x);
}

// ---------------------------------------------------------------------------
// gemm_gx: gx0[M=32768][384] = x[M][512] @ w_ih0[384][512]^T + b_ih0  (fp32)
// ---------------------------------------------------------------------------
__global__ __launch_bounds__(256) void gemm_gx(const float* __restrict__ A,
                                               const float* __restrict__ W,
                                               const float* __restrict__ bias,
                                               float* __restrict__ gx,
                                               int K)
{
    __shared__ __align__(16) float As[32][68];
    __shared__ __align__(16) float Bs[32][68];

    const int row0 = blockIdx.x * 64;
    const int col0 = blockIdx.y * 64;
    const int tid  = threadIdx.x;
    const int tx   = tid & 15;
    const int ty   = tid >> 4;
    const int r    = tid >> 2;
    const int kc   = (tid & 3) * 8;

    float acc[4][4] = {};

    for (int k0 = 0; k0 < K; k0 += 32) {
        {
            const float* Ap = A + (size_t)(row0 + r) * K + k0 + kc;
            float4 a0 = *(const float4*)(Ap);
            float4 a1 = *(const float4*)(Ap + 4);
            As[kc + 0][r] = a0.x; As[kc + 1][r] = a0.y; As[kc + 2][r] = a0.z; As[kc + 3][r] = a0.w;
            As[kc + 4][r] = a1.x; As[kc + 5][r] = a1.y; As[kc + 6][r] = a1.z; As[kc + 7][r] = a1.w;
        }
        {
            const float* Wp = W + (size_t)(col0 + r) * K + k0 + kc;
            float4 b0 = *(const float4*)(Wp);
            float4 b1 = *(const float4*)(Wp + 4);
            Bs[kc + 0][r] = b0.x; Bs[kc + 1][r] = b0.y; Bs[kc + 2][r] = b0.z; Bs[kc + 3][r] = b0.w;
            Bs[kc + 4][r] = b1.x; Bs[kc + 5][r] = b1.y; Bs[kc + 6][r] = b1.z; Bs[kc + 7][r] = b1.w;
        }
        __syncthreads();

        #pragma unroll
        for (int kk = 0; kk < 32; kk++) {
            float4 a = *(const float4*)&As[kk][ty * 4];
            float4 b = *(const float4*)&Bs[kk][tx * 4];
            acc[0][0] = fmaf(a.x, b.x, acc[0][0]); acc[0][1] = fmaf(a.x, b.y, acc[0][1]);
            acc[0][2] = fmaf(a.x, b.z, acc[0][2]); acc[0][3] = fmaf(a.x, b.w, acc[0][3]);
            acc[1][0] = fmaf(a.y, b.x, acc[1][0]); acc[1][1] = fmaf(a.y, b.y, acc[1][1]);
            acc[1][2] = fmaf(a.y, b.z, acc[1][2]); acc[1][3] = fmaf(a.y, b.w, acc[1][3]);
            acc[2][0] = fmaf(a.z, b.x, acc[2][0]); acc[2][1] = fmaf(a.z, b.y, acc[2][1]);
            acc[2][2] = fmaf(a.z, b.z, acc[2][2]); acc[2][3] = fmaf(a.z, b.w, acc[2][3]);
            acc[3][0] = fmaf(a.w, b.x, acc[3][0]); acc[3][1] = fmaf(a.w, b.y, acc[3][1]);
            acc[3][2] = fmaf(a.w, b.z, acc[3][2]); acc[3][3] = fmaf(a.w, b.w, acc[3][3]);
        }
        __syncthreads();
    }

    float bb[4];
    #pragma unroll
    for (int jj = 0; jj < 4; jj++) bb[jj] = bias[col0 + tx * 4 + jj];
    #pragma unroll
    for (int i = 0; i < 4; i++) {
        const int row = row0 + ty * 4 + i;
        float4 v;
        v.x = acc[i][0] + bb[0];
        v.y = acc[i][1] + bb[1];
        v.z = acc[i][2] + bb[2];
        v.w = acc[i][3] + bb[3];
        *(float4*)&gx[(size_t)row * G3 + col0 + tx * 4] = v;
    }
}

// ---------------------------------------------------------------------------
// gru_pipeline v7: R11 skeleton (chunked RELEASE/ACQUIRE, s_sleep spins,
// LDS flag barrier per step, real __syncthreads per chunk) but each block
// now owns TWO 16-batch groups (A,B). 10 blocks = 5 layers x 2 pairs.
// Rationale: the ~4000cyc step is latency/convergence dominated (R10==R11,
// R12 regression localized it); interleaving two independent streams in one
// wave fills the ds_read/MFMA/finalize latency with the other group's issue
// and halves barrier count per h-step. Weights shared between groups.
// ---------------------------------------------------------------------------
__global__ __launch_bounds__(512, 1) void gru_pipeline(
    const float* __restrict__ gx0,        // [64][512][384]
    const float* __restrict__ w_ih_rest,  // [4][384][128]
    const float* __restrict__ w_hh,       // [5][384][128]
    const float* __restrict__ b_ih,       // [5][384]
    const float* __restrict__ b_hh,       // [5][384]
    _Float16* __restrict__ hmid,          // [4][4][512][16][128]
    float* __restrict__ hlast,            // [64][128]
    int* __restrict__ flags)              // [8] = [layer][pair]
{
    const int l    = blockIdx.x >> 1;     // layer
    const int p    = blockIdx.x & 1;      // pair -> groups 2p, 2p+1
    const int gA   = 2 * p, gB = 2 * p + 1;
    const int tid  = threadIdx.x;
    const int lane = tid & 63;
    const int n16  = lane & 15;
    const int quad = lane >> 4;
    const int wv   = tid >> 6;
    const int j    = wv * 16 + n16;       // hidden index this lane finalizes

    __shared__ __align__(16) _Float16 hA[2][2][16][136];   // [group][buf][m][k]
    __shared__ int barcnt;

    // ---- B-frags for w_hh (shared by both groups) ----
    f16x8 bf[3][4];
    {
        const float* wb = w_hh + (size_t)l * G3 * HID;
        #pragma unroll
        for (int tau = 0; tau < 3; tau++)
            #pragma unroll
            for (int kc = 0; kc < 4; kc++) {
                const float* wp = wb + (size_t)(tau * 128 + j) * HID + kc * 32 + quad * 8;
                f16x8 v;
                #pragma unroll
                for (int i = 0; i < 8; i++) v[i] = (_Float16)wp[i];
                bf[tau][kc] = v;
            }
    }
    // ---- B-frags for w_ih (layers >= 1) ----
    f16x8 bi[3][4];
    if (l > 0) {
        const float* wb = w_ih_rest + (size_t)(l - 1) * G3 * HID;
        #pragma unroll
        for (int tau = 0; tau < 3; tau++)
            #pragma unroll
            for (int kc = 0; kc < 4; kc++) {
                const float* wp = wb + (size_t)(tau * 128 + j) * HID + kc * 32 + quad * 8;
                f16x8 v;
                #pragma unroll
                for (int i = 0; i < 8; i++) v[i] = (_Float16)wp[i];
                bi[tau][kc] = v;
            }
    }
    // folded gate biases (gx0 already contains b_ih for layer 0)
    const float bcr = b_hh[l * G3 + j]       + ((l > 0) ? b_ih[l * G3 + j]       : 0.f);
    const float bcz = b_hh[l * G3 + j + 128] + ((l > 0) ? b_ih[l * G3 + j + 128] : 0.f);
    const float bcn = b_hh[l * G3 + j + 256];
    const float bxn = (l > 0) ? b_ih[l * G3 + j + 256] : 0.f;

    // ---- zero h state ----
    for (int i = tid; i < 2 * 2 * 16 * 136; i += 512) ((_Float16*)hA)[i] = (_Float16)0.f;
    float vhpA[4] = {0.f, 0.f, 0.f, 0.f};
    float vhpB[4] = {0.f, 0.f, 0.f, 0.f};
    if (tid == 0) barcnt = 0;

    // ---- layer-0 gx pointers + preload t=0 (both groups) ----
    const float* pRA[4]; const float* pRB[4];
    float xrA[4], xzA[4], xnA[4], xrB[4], xzB[4], xnB[4];
    if (l == 0) {
        #pragma unroll
        for (int r = 0; r < 4; r++) {
            pRA[r] = gx0 + (size_t)(gA * 16 + quad * 4 + r) * SEQ * G3 + j;
            pRB[r] = gx0 + (size_t)(gB * 16 + quad * 4 + r) * SEQ * G3 + j;
            xrA[r] = pRA[r][0]; xzA[r] = pRA[r][128]; xnA[r] = pRA[r][256]; pRA[r] += G3;
            xrB[r] = pRB[r][0]; xzB[r] = pRB[r][128]; xnB[r] = pRB[r][256]; pRB[r] += G3;
        }
    }

    const _Float16* hprevA = (l > 0) ? hmid + (size_t)((l - 1) * 4 + gA) * SEQ * 2048 : (const _Float16*)nullptr;
    const _Float16* hprevB = (l > 0) ? hmid + (size_t)((l - 1) * 4 + gB) * SEQ * 2048 : (const _Float16*)nullptr;
    _Float16* hpubA = (l < 4) ? hmid + (size_t)(l * 4 + gA) * SEQ * 2048 : (_Float16*)nullptr;
    _Float16* hpubB = (l < 4) ? hmid + (size_t)(l * 4 + gB) * SEQ * 2048 : (_Float16*)nullptr;
    int*       dstflag = (l < 4) ? &flags[l * 2 + p] : (int*)nullptr;
    const int* srcflag = (l > 0) ? &flags[(l - 1) * 2 + p] : (const int*)nullptr;

    _Float16* hwA = (l < 4) ? hpubA + quad * 4 * 128 + j : (_Float16*)nullptr;
    _Float16* hwB = (l < 4) ? hpubB + quad * 4 * 128 + j : (_Float16*)nullptr;

    f16x8 apA[4], apB[4];
    const int hoff = n16 * 128 + quad * 8;   // A-frag base (m=n16, k=quad*8)

    __syncthreads();   // hA zero + barcnt visible

    volatile int* bc = &barcnt;
    int btarget = 0;

    for (int c = 0; c < SEQ / CHUNK; c++) {
        const int t0 = c * CHUNK;

        if (l > 0) {
            // once-per-chunk: relaxed spin, then ONE acquire load (buffer_inv)
            const int need = t0 + CHUNK;
            int v = __hip_atomic_load(srcflag, __ATOMIC_RELAXED, __HIP_MEMORY_SCOPE_AGENT);
            while (v < need) {
                __builtin_amdgcn_s_sleep(2);
                v = __hip_atomic_load(srcflag, __ATOMIC_RELAXED, __HIP_MEMORY_SCOPE_AGENT);
            }
            (void)__hip_atomic_load(srcflag, __ATOMIC_ACQUIRE, __HIP_MEMORY_SCOPE_AGENT);
            __asm__ volatile("" ::: "memory");
            const _Float16* hpa = hprevA + (size_t)t0 * 2048 + hoff;
            const _Float16* hpb = hprevB + (size_t)t0 * 2048 + hoff;
            #pragma unroll
            for (int kc = 0; kc < 4; kc++) { apA[kc] = *(const f16x8*)(hpa + kc * 32);
                                             apB[kc] = *(const f16x8*)(hpb + kc * 32); }
        }

        #pragma unroll
        for (int i = 0; i < CHUNK; i++) {
            const int t = t0 + i;

            // ---- LDS flag barrier (no vmcnt drain) ----
            __asm__ volatile("" ::: "memory");
            if (lane == 0) atomicAdd(&barcnt, 1);
            btarget += 8;
            while (*bc < btarget) { __builtin_amdgcn_s_sleep(1); }
            __asm__ volatile("" ::: "memory");

            const int buf = t & 1;
            // group A: af loads, ih MFMAs (fill LDS latency), hh MFMAs
            f16x8 afA[4];
            #pragma unroll
            for (int kc = 0; kc < 4; kc++)
                afA[kc] = *(const f16x8*)&hA[0][buf][n16][kc * 32 + quad * 8];
            f32x4 aiA0 = {0.f,0.f,0.f,0.f}, aiA1 = aiA0, aiA2 = aiA0;
            if (l > 0) {
                #pragma unroll
                for (int kc = 0; kc < 4; kc++) {
                    aiA0 = __builtin_amdgcn_mfma_f32_16x16x32_f16(apA[kc], bi[0][kc], aiA0, 0, 0, 0);
                    aiA1 = __builtin_amdgcn_mfma_f32_16x16x32_f16(apA[kc], bi[1][kc], aiA1, 0, 0, 0);
                    aiA2 = __builtin_amdgcn_mfma_f32_16x16x32_f16(apA[kc], bi[2][kc], aiA2, 0, 0, 0);
                }
            }
            f32x4 ahA0 = {0.f,0.f,0.f,0.f}, ahA1 = ahA0, ahA2 = ahA0;
            #pragma unroll
            for (int kc = 0; kc < 4; kc++) {
                ahA0 = __builtin_amdgcn_mfma_f32_16x16x32_f16(afA[kc], bf[0][kc], ahA0, 0, 0, 0);
                ahA1 = __builtin_amdgcn_mfma_f32_16x16x32_f16(afA[kc], bf[1][kc], ahA1, 0, 0, 0);
                ahA2 = __builtin_amdgcn_mfma_f32_16x16x32_f16(afA[kc], bf[2][kc], ahA2, 0, 0, 0);
            }

            // group B: af loads, ih MFMAs, hh MFMAs (fills A's MFMA latency)
            f16x8 afB[4];
            #pragma unroll
            for (int kc = 0; kc < 4; kc++)
                afB[kc] = *(const f16x8*)&hA[1][buf][n16][kc * 32 + quad * 8];
            f32x4 aiB0 = {0.f,0.f,0.f,0.f}, aiB1 = aiB0, aiB2 = aiB0;
            if (l > 0) {
                #pragma unroll
                for (int kc = 0; kc < 4; kc++) {
                    aiB0 = __builtin_amdgcn_mfma_f32_16x16x32_f16(apB[kc], bi[0][kc], aiB0, 0, 0, 0);
                    aiB1 = __builtin_amdgcn_mfma_f32_16x16x32_f16(apB[kc], bi[1][kc], aiB1, 0, 0, 0);
                    aiB2 = __builtin_amdgcn_mfma_f32_16x16x32_f16(apB[kc], bi[2][kc], aiB2, 0, 0, 0);
                }
            }
            f32x4 ahB0 = {0.f,0.f,0.f,0.f}, ahB1 = ahB0, ahB2 = ahB0;
            #pragma unroll
            for (int kc = 0; kc < 4; kc++) {
                ahB0 = __builtin_amdgcn_mfma_f32_16x16x32_f16(afB[kc], bf[0][kc], ahB0, 0, 0, 0);
                ahB1 = __builtin_amdgcn_mfma_f32_16x16x32_f16(afB[kc], bf[1][kc], ahB1, 0, 0, 0);
                ahB2 = __builtin_amdgcn_mfma_f32_16x16x32_f16(afB[kc], bf[2][kc], ahB2, 0, 0, 0);
            }

            // layer-0: gx(t+1) prefetch (both groups)
            float nrA[4], nzA[4], nnA[4], nrB[4], nzB[4], nnB[4];
            if (l == 0) {
                #pragma unroll
                for (int r = 0; r < 4; r++) {
                    nrA[r] = pRA[r][0]; nzA[r] = pRA[r][128]; nnA[r] = pRA[r][256];
                    nrB[r] = pRB[r][0]; nzB[r] = pRB[r][128]; nnB[r] = pRB[r][256];
                }
                if (t + 1 < SEQ) {
                    #pragma unroll
                    for (int r = 0; r < 4; r++) { pRA[r] += G3; pRB[r] += G3; }
                }
            }

            const int nbuf = buf ^ 1;
            // finalize A (B's MFMAs in flight behind it)
            #pragma unroll
            for (int r = 0; r < 4; r++) {
                const float sxr = (l == 0) ? xrA[r] : aiA0[r];
                const float sxz = (l == 0) ? xzA[r] : aiA1[r];
                const float sxn = ((l == 0) ? xnA[r] : aiA2[r]) + bxn;
                const float rg  = sigf(sxr + ahA0[r] + bcr);
                const float zg  = sigf(sxz + ahA1[r] + bcz);
                const float th  = tanh_fast(sxn + rg * (ahA2[r] + bcn));
                const float hnew = fmaf(zg, vhpA[r] - th, th);
                vhpA[r] = hnew;
                hA[0][nbuf][quad * 4 + r][j] = (_Float16)hnew;
                if (l < 4) hwA[r * 128] = (_Float16)hnew;
                if (l == 4 && t == SEQ - 1) hlast[(gA * 16 + quad * 4 + r) * 128 + j] = hnew;
            }
            // finalize B
            #pragma unroll
            for (int r = 0; r < 4; r++) {
                const float sxr = (l == 0) ? xrB[r] : aiB0[r];
                const float sxz = (l == 0) ? xzB[r] : aiB1[r];
                const float sxn = ((l == 0) ? xnB[r] : aiB2[r]) + bxn;
                const float rg  = sigf(sxr + ahB0[r] + bcr);
                const float zg  = sigf(sxz + ahB1[r] + bcz);
                const float th  = tanh_fast(sxn + rg * (ahB2[r] + bcn));
                const float hnew = fmaf(zg, vhpB[r] - th, th);
                vhpB[r] = hnew;
                hA[1][nbuf][quad * 4 + r][j] = (_Float16)hnew;
                if (l < 4) hwB[r * 128] = (_Float16)hnew;
                if (l == 4 && t == SEQ - 1) hlast[(gB * 16 + quad * 4 + r) * 128 + j] = hnew;
            }
            if (l < 4) { hwA += 2048; hwB += 2048; }

            if (l == 0) {
                #pragma unroll
                for (int r = 0; r < 4; r++) {
                    xrA[r] = nrA[r]; xzA[r] = nzA[r]; xnA[r] = nnA[r];
                    xrB[r] = nrB[r]; xzB[r] = nzB[r]; xnB[r] = nnB[r];
                }
            }

            // in-chunk prefetch of h_prev(t+1) (covered by this chunk's acquire)
            if (l > 0 && i < CHUNK - 1) {
                const _Float16* hpa = hprevA + (size_t)(t + 1) * 2048 + hoff;
                const _Float16* hpb = hprevB + (size_t)(t + 1) * 2048 + hoff;
                #pragma unroll
                for (int kc = 0; kc < 4; kc++) { apA[kc] = *(const f16x8*)(hpa + kc * 32);
                                                 apB[kc] = *(const f16x8*)(hpb + kc * 32); }
            }
        }

        // ---- chunk boundary: REAL barrier (drains hpub stores), then RELEASE
        __syncthreads();
        if (l < 4 && tid == 0)
            __hip_atomic_store(dstflag, t0 + CHUNK, __ATOMIC_RELEASE, __HIP_MEMORY_SCOPE_AGENT);
    }
}

// ---------------------------------------------------------------------------
// fc: out[b][o] = hlast[b][:] . fc_w[o][:] + fc_b[o]
// ---------------------------------------------------------------------------
__global__ __launch_bounds__(128) void fc_kernel(const float* __restrict__ hlast,
                                                 const float* __restrict__ fc_w,
                                                 const float* __restrict__ fc_b,
                                                 float* __restrict__ out)
{
    const int b = blockIdx.x;
    const int o = threadIdx.x;
    if (o < 96) {
        const float* h = hlast + (size_t)b * HID;
        const float* wrow = fc_w + o * HID;
        float acc = fc_b[o];
        #pragma unroll 4
        for (int k = 0; k < HID; k++) acc = fmaf(h[k], wrow[k], acc);
        out[b * 96 + o] = acc;
    }
}

// ---------------------------------------------------------------------------
extern "C" void kernel_launch(void* const* d_in, const int* in_sizes, int n_in,
                              void* d_out, int out_size, void* d_ws, size_t ws_size,
                              hipStream_t stream)
{
    const float* x         = (const float*)d_in[0]; // [64][512][512]
    const float* w_ih0     = (const float*)d_in[1]; // [384][512]
    const float* w_ih_rest = (const float*)d_in[2]; // [4][384][128]
    const float* w_hh      = (const float*)d_in[3]; // [5][384][128]
    const float* b_ih      = (const float*)d_in[4]; // [5][384]
    const float* b_hh      = (const float*)d_in[5]; // [5][384]
    const float* fc_w      = (const float*)d_in[6]; // [96][128]
    const float* fc_b      = (const float*)d_in[7]; // [96]
    float* out = (float*)d_out;                     // [64][96]

    // workspace layout:
    //   [0,256)              flags (8 ints, zeroed each launch)
    //   [256, +50331648)     gxbuf fp32 [64][512][384]
    //   [.., +33554432)      hmid  f16  [4][4][512][16][128]
    //   [.., +32768)         hlast fp32 [64][128]
    int*      flags = (int*)d_ws;
    float*    gxbuf = (float*)((char*)d_ws + 256);
    _Float16* hmid  = (_Float16*)((char*)d_ws + 256 + 50331648);
    float*    hlast = (float*)((char*)d_ws + 256 + 50331648 + 33554432);

    hipMemsetAsync(d_ws, 0, 256, stream);

    const dim3 gemmGrid(512, 6);
    gemm_gx<<<gemmGrid, 256, 0, stream>>>(x, w_ih0, b_ih, gxbuf, IN0);

    gru_pipeline<<<NLAY * 2, 512, 0, stream>>>(gxbuf, w_ih_rest, w_hh, b_ih, b_hh,
                                               hmid, hlast, flags);

    fc_kernel<<<BATCH, 128, 0, stream>>>(hlast, fc_w, fc_b, out);
}

// Round 14
// 983.929 us; speedup vs baseline: 3.0767x; 3.0767x over previous
//
#include <hip/hip_runtime.h>
#include <hip/hip_bf16.h>

// Problem constants
#define BATCH   64
#define SEQ     512
#define IN0     512
#define HID     128
#define G3      384   // 3*HID
#define NLAY    5
#define CHUNK   8     // handoff granularity (one release/acquire per CHUNK steps)

typedef _Float16 f16x8 __attribute__((ext_vector_type(8)));
typedef float    f32x4 __attribute__((ext_vector_type(4)));

static __device__ __forceinline__ float sigf(float x) {
    return __builtin_amdgcn_rcpf(1.f + __expf(-x));
}
static __device__ __forceinline__ float tanh_fast(float x) {
    const float e = __expf(-2.f * fabsf(x));
    return copysignf((1.f - e) * __builtin_amdgcn_rcpf(1.f + e), x);
}

// ---------------------------------------------------------------------------
// gemm_gx (MFMA): gx0[32768][384] = x[32768][512] @ w_ih0[384][512]^T + b_ih0
// f16 inputs / fp32 accumulate via mfma_f32_16x16x32_f16.
// Block 256 thr = 4 waves; tile M=64 x N=64; wave wv owns m-subtile wv*16,
// 4 N-subtiles of 16 -> 4 accs. K-chunk 32: A-frag = one f16x8 per lane
// (m=lane&15, k=quad*8+i), B-frag likewise (n=lane&15). C: row=quad*4+reg,
// col=lane&15 (layouts HW-verified by the scan kernel).
// ---------------------------------------------------------------------------
__global__ __launch_bounds__(256) void gemm_gx(const float* __restrict__ A,
                                               const float* __restrict__ W,
                                               const float* __restrict__ bias,
                                               float* __restrict__ gx)
{
    __shared__ __align__(16) _Float16 As[64][40];   // [m][k0..31], pad 40 (80B rows)
    __shared__ __align__(16) _Float16 Bs[64][40];   // [n][k0..31]

    const int tid  = threadIdx.x;
    const int lane = tid & 63;
    const int wv   = tid >> 6;          // m-subtile
    const int n16  = lane & 15;
    const int quad = lane >> 4;
    const int row0 = blockIdx.x * 64;
    const int col0 = blockIdx.y * 64;
    const int r    = tid >> 2;          // staging row 0..63
    const int kc   = (tid & 3) * 8;     // staging k offset 0,8,16,24

    f32x4 acc[4];
    #pragma unroll
    for (int nt = 0; nt < 4; nt++) acc[nt] = (f32x4){0.f, 0.f, 0.f, 0.f};

    for (int k0 = 0; k0 < IN0; k0 += 32) {
        // ---- stage A (x) tile, f32 -> f16 ----
        {
            const float* Ap = A + (size_t)(row0 + r) * IN0 + k0 + kc;
            float4 a0 = *(const float4*)(Ap);
            float4 a1 = *(const float4*)(Ap + 4);
            f16x8 v;
            v[0] = (_Float16)a0.x; v[1] = (_Float16)a0.y; v[2] = (_Float16)a0.z; v[3] = (_Float16)a0.w;
            v[4] = (_Float16)a1.x; v[5] = (_Float16)a1.y; v[6] = (_Float16)a1.z; v[7] = (_Float16)a1.w;
            *(f16x8*)&As[r][kc] = v;
        }
        // ---- stage B (w_ih0) tile ----
        {
            const float* Wp = W + (size_t)(col0 + r) * IN0 + k0 + kc;
            float4 b0 = *(const float4*)(Wp);
            float4 b1 = *(const float4*)(Wp + 4);
            f16x8 v;
            v[0] = (_Float16)b0.x; v[1] = (_Float16)b0.y; v[2] = (_Float16)b0.z; v[3] = (_Float16)b0.w;
            v[4] = (_Float16)b1.x; v[5] = (_Float16)b1.y; v[6] = (_Float16)b1.z; v[7] = (_Float16)b1.w;
            *(f16x8*)&Bs[r][kc] = v;
        }
        __syncthreads();

        const f16x8 af = *(const f16x8*)&As[wv * 16 + n16][quad * 8];
        #pragma unroll
        for (int nt = 0; nt < 4; nt++) {
            const f16x8 bfr = *(const f16x8*)&Bs[nt * 16 + n16][quad * 8];
            acc[nt] = __builtin_amdgcn_mfma_f32_16x16x32_f16(af, bfr, acc[nt], 0, 0, 0);
        }
        __syncthreads();
    }

    // epilogue: bias + store (lane owns rows quad*4+r4 of subtile, col n16)
    #pragma unroll
    for (int nt = 0; nt < 4; nt++) {
        const int col = col0 + nt * 16 + n16;
        const float bb = bias[col];
        #pragma unroll
        for (int r4 = 0; r4 < 4; r4++) {
            const int row = row0 + wv * 16 + quad * 4 + r4;
            gx[(size_t)row * G3 + col] = acc[nt][r4] + bb;
        }
    }
}

// ---------------------------------------------------------------------------
// gru_pipeline (R11 verbatim — proven 848 us):
// chunked RELEASE/ACQUIRE handoff, per-step LDS flag barrier, ih-MFMAs after
// barrier with af ds_reads issued first, folded biases, s_sleep spins.
// ---------------------------------------------------------------------------
__global__ __launch_bounds__(512, 2) void gru_pipeline(
    const float* __restrict__ gx0,        // [64][512][384]
    const float* __restrict__ w_ih_rest,  // [4][384][128]
    const float* __restrict__ w_hh,       // [5][384][128]
    const float* __restrict__ b_ih,       // [5][384]
    const float* __restrict__ b_hh,       // [5][384]
    _Float16* __restrict__ hmid,          // [4][4][512][16][128]
    float* __restrict__ hlast,            // [64][128]
    int* __restrict__ flags)              // [16]
{
    const int l    = blockIdx.x >> 2;
    const int g    = blockIdx.x & 3;
    const int bm0  = g * 16;
    const int tid  = threadIdx.x;
    const int lane = tid & 63;
    const int n16  = lane & 15;
    const int quad = lane >> 4;
    const int wv   = tid >> 6;
    const int j    = wv * 16 + n16;       // hidden index this lane finalizes

    __shared__ __align__(16) _Float16 hA[2][16][136];
    __shared__ int barcnt;

    // ---- B-frags for w_hh ----
    f16x8 bf[3][4];
    {
        const float* wb = w_hh + (size_t)l * G3 * HID;
        #pragma unroll
        for (int tau = 0; tau < 3; tau++)
            #pragma unroll
            for (int kc = 0; kc < 4; kc++) {
                const float* wp = wb + (size_t)(tau * 128 + j) * HID + kc * 32 + quad * 8;
                f16x8 v;
                #pragma unroll
                for (int i = 0; i < 8; i++) v[i] = (_Float16)wp[i];
                bf[tau][kc] = v;
            }
    }
    // ---- B-frags for w_ih (layers >= 1) ----
    f16x8 bi[3][4];
    if (l > 0) {
        const float* wb = w_ih_rest + (size_t)(l - 1) * G3 * HID;
        #pragma unroll
        for (int tau = 0; tau < 3; tau++)
            #pragma unroll
            for (int kc = 0; kc < 4; kc++) {
                const float* wp = wb + (size_t)(tau * 128 + j) * HID + kc * 32 + quad * 8;
                f16x8 v;
                #pragma unroll
                for (int i = 0; i < 8; i++) v[i] = (_Float16)wp[i];
                bi[tau][kc] = v;
            }
    }
    // folded gate biases (gx0 already contains b_ih for layer 0)
    const float bcr = b_hh[l * G3 + j]       + ((l > 0) ? b_ih[l * G3 + j]       : 0.f);
    const float bcz = b_hh[l * G3 + j + 128] + ((l > 0) ? b_ih[l * G3 + j + 128] : 0.f);
    const float bcn = b_hh[l * G3 + j + 256];                      // n-gate: b_hh inside r*(...)
    const float bxn = (l > 0) ? b_ih[l * G3 + j + 256] : 0.f;      // n-gate: b_ih outside

    // ---- zero h state ----
    for (int i = tid; i < 2 * 16 * 136; i += 512) ((_Float16*)hA)[i] = (_Float16)0.f;
    float vhp[4] = {0.f, 0.f, 0.f, 0.f};
    if (tid == 0) barcnt = 0;

    // ---- layer-0 gx pointers + preload t=0 ----
    const float* pR[4];
    float xr[4], xz[4], xn[4];
    if (l == 0) {
        #pragma unroll
        for (int r = 0; r < 4; r++) {
            pR[r] = gx0 + (size_t)(bm0 + quad * 4 + r) * SEQ * G3 + j;
            xr[r] = pR[r][0]; xz[r] = pR[r][128]; xn[r] = pR[r][256];
            pR[r] += G3;
        }
    }

    const _Float16* hprev = (l > 0) ? hmid + (size_t)((l - 1) * 4 + g) * SEQ * 2048 : (const _Float16*)nullptr;
    _Float16*       hpub  = (l < 4) ? hmid + (size_t)(l * 4 + g) * SEQ * 2048 : (_Float16*)nullptr;
    int*       dstflag = (l < 4) ? &flags[l * 4 + g] : (int*)nullptr;
    const int* srcflag = (l > 0) ? &flags[(l - 1) * 4 + g] : (const int*)nullptr;

    _Float16* hw = (l < 4) ? hpub + quad * 4 * 128 + j : (_Float16*)nullptr;  // walks by 2048/step

    f16x8 ap[4];                             // h_prev(t) A-frags
    const int hoff = n16 * 128 + quad * 8;   // A-frag base (m=n16, k=quad*8)

    __syncthreads();   // hA zero + barcnt visible

    volatile int* bc = &barcnt;
    int btarget = 0;

    for (int c = 0; c < SEQ / CHUNK; c++) {
        const int t0 = c * CHUNK;

        if (l > 0) {
            // once-per-chunk: relaxed spin, then ONE acquire load (buffer_inv)
            const int need = t0 + CHUNK;
            int v = __hip_atomic_load(srcflag, __ATOMIC_RELAXED, __HIP_MEMORY_SCOPE_AGENT);
            while (v < need) {
                __builtin_amdgcn_s_sleep(2);
                v = __hip_atomic_load(srcflag, __ATOMIC_RELAXED, __HIP_MEMORY_SCOPE_AGENT);
            }
            (void)__hip_atomic_load(srcflag, __ATOMIC_ACQUIRE, __HIP_MEMORY_SCOPE_AGENT);
            __asm__ volatile("" ::: "memory");
            const _Float16* hp = hprev + (size_t)t0 * 2048 + hoff;
            #pragma unroll
            for (int kc = 0; kc < 4; kc++) ap[kc] = *(const f16x8*)(hp + kc * 32);
        }

        #pragma unroll
        for (int i = 0; i < CHUNK; i++) {
            const int t = t0 + i;

            // ---- LDS flag barrier: no vmcnt drain (stores stay in flight) ----
            __asm__ volatile("" ::: "memory");
            if (lane == 0) atomicAdd(&barcnt, 1);
            btarget += 8;
            while (*bc < btarget) { __builtin_amdgcn_s_sleep(1); }
            __asm__ volatile("" ::: "memory");

            const int buf = t & 1;
            // issue af LDS reads first (latency overlapped by ih MFMAs below)
            f16x8 af[4];
            #pragma unroll
            for (int kc = 0; kc < 4; kc++)
                af[kc] = *(const f16x8*)&hA[buf][n16][kc * 32 + quad * 8];

            // ih MFMAs (register inputs, no LDS dependency) — issue first
            f32x4 ai0 = {0.f,0.f,0.f,0.f}, ai1 = ai0, ai2 = ai0;
            if (l > 0) {
                #pragma unroll
                for (int kc = 0; kc < 4; kc++) {
                    ai0 = __builtin_amdgcn_mfma_f32_16x16x32_f16(ap[kc], bi[0][kc], ai0, 0, 0, 0);
                    ai1 = __builtin_amdgcn_mfma_f32_16x16x32_f16(ap[kc], bi[1][kc], ai1, 0, 0, 0);
                    ai2 = __builtin_amdgcn_mfma_f32_16x16x32_f16(ap[kc], bi[2][kc], ai2, 0, 0, 0);
                }
            }
            // layer-0: issue gx(t+1) prefetch
            float nr[4], nz[4], nn[4];
            if (l == 0) {
                #pragma unroll
                for (int r = 0; r < 4; r++) {
                    nr[r] = pR[r][0]; nz[r] = pR[r][128]; nn[r] = pR[r][256];
                }
                if (t + 1 < SEQ) {
                    #pragma unroll
                    for (int r = 0; r < 4; r++) pR[r] += G3;
                }
            }

            // hh MFMAs
            f32x4 ah0 = {0.f,0.f,0.f,0.f}, ah1 = ah0, ah2 = ah0;
            #pragma unroll
            for (int kc = 0; kc < 4; kc++) {
                ah0 = __builtin_amdgcn_mfma_f32_16x16x32_f16(af[kc], bf[0][kc], ah0, 0, 0, 0);
                ah1 = __builtin_amdgcn_mfma_f32_16x16x32_f16(af[kc], bf[1][kc], ah1, 0, 0, 0);
                ah2 = __builtin_amdgcn_mfma_f32_16x16x32_f16(af[kc], bf[2][kc], ah2, 0, 0, 0);
            }

            // finalize: lane owns (m = quad*4+r, j) for all gates
            const int nbuf = buf ^ 1;
            #pragma unroll
            for (int r = 0; r < 4; r++) {
                const float sxr = (l == 0) ? xr[r] : ai0[r];
                const float sxz = (l == 0) ? xz[r] : ai1[r];
                const float sxn = ((l == 0) ? xn[r] : ai2[r]) + bxn;
                const float rg  = sigf(sxr + ah0[r] + bcr);
                const float zg  = sigf(sxz + ah1[r] + bcz);
                const float th  = tanh_fast(sxn + rg * (ah2[r] + bcn));
                const float hnew = fmaf(zg, vhp[r] - th, th);   // (1-z)n + z h
                vhp[r] = hnew;
                hA[nbuf][quad * 4 + r][j] = (_Float16)hnew;
                if (l < 4) hw[r * 128] = (_Float16)hnew;        // drains at chunk-end syncthreads
                if (l == 4 && t == SEQ - 1)
                    hlast[(bm0 + quad * 4 + r) * 128 + j] = hnew;
            }
            if (l < 4) hw += 2048;

            if (l == 0) {
                #pragma unroll
                for (int r = 0; r < 4; r++) { xr[r] = nr[r]; xz[r] = nz[r]; xn[r] = nn[r]; }
            }

            // in-chunk prefetch of h_prev(t+1) (covered by this chunk's acquire)
            if (l > 0 && i < CHUNK - 1) {
                const _Float16* hp = hprev + (size_t)(t + 1) * 2048 + hoff;
                #pragma unroll
                for (int kc = 0; kc < 4; kc++) ap[kc] = *(const f16x8*)(hp + kc * 32);
            }
        }

        // ---- chunk boundary: REAL barrier (drains hpub stores), then RELEASE
        __syncthreads();
        if (l < 4 && tid == 0)
            __hip_atomic_store(dstflag, t0 + CHUNK, __ATOMIC_RELEASE, __HIP_MEMORY_SCOPE_AGENT);
    }
}

// ---------------------------------------------------------------------------
// fc: out[b][o] = hlast[b][:] . fc_w[o][:] + fc_b[o]
// ---------------------------------------------------------------------------
__global__ __launch_bounds__(128) void fc_kernel(const float* __restrict__ hlast,
                                                 const float* __restrict__ fc_w,
                                                 const float* __restrict__ fc_b,
                                                 float* __restrict__ out)
{
    const int b = blockIdx.x;
    const int o = threadIdx.x;
    if (o < 96) {
        const float* h = hlast + (size_t)b * HID;
        const float* wrow = fc_w + o * HID;
        float acc = fc_b[o];
        #pragma unroll 4
        for (int k = 0; k < HID; k++) acc = fmaf(h[k], wrow[k], acc);
        out[b * 96 + o] = acc;
    }
}

// ---------------------------------------------------------------------------
extern "C" void kernel_launch(void* const* d_in, const int* in_sizes, int n_in,
                              void* d_out, int out_size, void* d_ws, size_t ws_size,
                              hipStream_t stream)
{
    const float* x         = (const float*)d_in[0]; // [64][512][512]
    const float* w_ih0     = (const float*)d_in[1]; // [384][512]
    const float* w_ih_rest = (const float*)d_in[2]; // [4][384][128]
    const float* w_hh      = (const float*)d_in[3]; // [5][384][128]
    const float* b_ih      = (const float*)d_in[4]; // [5][384]
    const float* b_hh      = (const float*)d_in[5]; // [5][384]
    const float* fc_w      = (const float*)d_in[6]; // [96][128]
    const float* fc_b      = (const float*)d_in[7]; // [96]
    float* out = (float*)d_out;                     // [64][96]

    // workspace layout:
    //   [0,256)              flags (16 ints, zeroed each launch)
    //   [256, +50331648)     gxbuf fp32 [64][512][384]
    //   [.., +33554432)      hmid  f16  [4][4][512][16][128]
    //   [.., +32768)         hlast fp32 [64][128]
    int*      flags = (int*)d_ws;
    float*    gxbuf = (float*)((char*)d_ws + 256);
    _Float16* hmid  = (_Float16*)((char*)d_ws + 256 + 50331648);
    float*    hlast = (float*)((char*)d_ws + 256 + 50331648 + 33554432);

    hipMemsetAsync(d_ws, 0, 256, stream);

    const dim3 gemmGrid(512, 6);
    gemm_gx<<<gemmGrid, 256, 0, stream>>>(x, w_ih0, b_ih, gxbuf);

    gru_pipeline<<<NLAY * 4, 512, 0, stream>>>(gxbuf, w_ih_rest, w_hh, b_ih, b_hh,
                                               hmid, hlast, flags);

    fc_kernel<<<BATCH, 128, 0, stream>>>(hlast, fc_w, fc_b, out);
}